// Round 5
// baseline (294.492 us; speedup 1.0000x reference)
//
#include <hip/hip_runtime.h>

#define H 1024
#define E 8
#define BLK 256
#define CAP 5120       // int(1.25 * 4096 * 8 / 8)
#define FBLK 1024
#define TPW 8          // tokens per wave

typedef float f32x4 __attribute__((ext_vector_type(4)));

// ---------------------------------------------------------------------------
// Kernel 1: contiguous-stream GEMV, register-light, spill-proofed.
// R4 post-mortem: counters were BIT-IDENTICAL to R3 (WRITE 116MB, VGPR 64)
// -> the lambda address-escape theory was wrong (inlining+SROA handles it).
// Real cause: FULL UNROLL of the t-loop made every refill load unconditional
// and hoistable; the scheduler clustered ~3 future t-steps of A-data (~96
// regs) early -> pressure >> 128 cap -> allocator spilled the A-buffers
// wholesale (512B/thread scratch x 262k threads = the 114MB excess WRITE,
// +40MB reload FETCH; VGPR_Count=64 is the post-spill residue).
// Fix: `#pragma unroll 1` on the t-loop. Rolled loop = refills are
// loop-carried, future iterations' loads CANNOT be hoisted; A-liveness caps
// at one depth-2 window (~32 regs). q/e inner loops stay fully unrolled
// (all indices static -- no rule-#20 scratch trap).
// Unchanged from R3/R4 (design validated: 0 bank conflicts, occ 40%):
//  - w in LDS (32KB); lane l reads w[e][q] at (e*1024+q*256+4l): 16B/lane
//    contiguous ds_read_b128, conflict-free.
//  - hs loads 1KB-contiguous per wave (lane l owns floats {4l+256q} of one
//    row), depth-2 token prefetch staggered through the q-loop.
//  - reduce-scatter (masks 1,2,4 keep/send, 8,16,32 add) -> lane 8g+e holds
//    logit(token g, expert e); 10 shfl/token.
//  - epilogue: group-of-8 softmax/top2 butterflies, all 64 lanes active;
//    dispatch/probs stores one dword/lane, 256B contiguous.
// ---------------------------------------------------------------------------
__global__ __launch_bounds__(BLK, 4) void router_kernel(
    const float* __restrict__ hs,
    const float* __restrict__ rw,
    float* __restrict__ dispatch,
    float* __restrict__ probs_out,
    float* __restrict__ partial)   // [16][nb] slot-major
{
    __shared__ float w_lds[E * H];   // 32 KB
    __shared__ float red[4][16];

    const int tid  = threadIdx.x;
    const int wave = tid >> 6;
    const int lane = tid & 63;
    const int g    = lane >> 3;      // token group within wave (0..7)
    const int eo   = lane & 7;       // owned expert
    const size_t tok0 = ((size_t)blockIdx.x * (BLK / 64) + wave) * TPW;
    const float* h0 = hs + tok0 * H + 4 * lane;

    // depth-2 token prefetch (8 x 1KB contiguous wave-loads), issued before
    // the w staging so the HBM round-trip overlaps it
    f32x4 A0[4], A1[4];
#pragma unroll
    for (int q = 0; q < 4; ++q) A0[q] = *(const f32x4*)(h0 + q * 256);
#pragma unroll
    for (int q = 0; q < 4; ++q) A1[q] = *(const f32x4*)(h0 + H + q * 256);

    for (int i = tid; i < E * H / 4; i += BLK)
        ((f32x4*)w_lds)[i] = ((const f32x4*)rw)[i];
    __syncthreads();

    const int b0 = lane & 1, b1 = (lane >> 1) & 1, b2 = (lane >> 2) & 1;

    // reduce-scatter over the 8-expert set (inputs by value; after inlining
    // everything is SSA). Output: full dot for expert (lane&7), replicated
    // over the 8-lane groups.
    auto rscatter = [&](float a0, float a1, float a2, float a3,
                        float a4, float a5, float a6, float a7) -> float {
        float r0 = b0 ? a1 : a0, s0 = b0 ? a0 : a1;
        float r1 = b0 ? a3 : a2, s1 = b0 ? a2 : a3;
        float r2 = b0 ? a5 : a4, s2 = b0 ? a4 : a5;
        float r3 = b0 ? a7 : a6, s3 = b0 ? a6 : a7;
        r0 += __shfl_xor(s0, 1); r1 += __shfl_xor(s1, 1);
        r2 += __shfl_xor(s2, 1); r3 += __shfl_xor(s3, 1);
        float t0 = b1 ? r1 : r0, u0 = b1 ? r0 : r1;
        float t1 = b1 ? r3 : r2, u1 = b1 ? r2 : r3;
        t0 += __shfl_xor(u0, 2); t1 += __shfl_xor(u1, 2);
        float v = b2 ? t1 : t0, x = b2 ? t0 : t1;
        v += __shfl_xor(x, 4);
        v += __shfl_xor(v, 8);
        v += __shfl_xor(v, 16);
        v += __shfl_xor(v, 32);
        return v;                 // logit for expert 4*b2+2*b1+b0 = lane&7
    };

    float mylog = 0.f;            // latched logit for (token tok0+g, expert eo)
    const float* pnext = h0 + 2 * H;

#pragma unroll 1   // ROLLED: forbids cross-iteration hoist of refill loads
    for (int t = 0; t < TPW; t += 2) {
        float acc0[E], acc1[E];
#pragma unroll
        for (int e = 0; e < E; ++e) { acc0[e] = 0.f; acc1[e] = 0.f; }

#pragma unroll
        for (int q = 0; q < 4; ++q) {
            const float* wb = w_lds + q * 256 + 4 * lane;
#pragma unroll
            for (int e = 0; e < E; ++e) {
                const f32x4 wv = *(const f32x4*)(wb + e * H);
                acc0[e] = fmaf(A0[q][0], wv[0], acc0[e]);
                acc0[e] = fmaf(A0[q][1], wv[1], acc0[e]);
                acc0[e] = fmaf(A0[q][2], wv[2], acc0[e]);
                acc0[e] = fmaf(A0[q][3], wv[3], acc0[e]);
                acc1[e] = fmaf(A1[q][0], wv[0], acc1[e]);
                acc1[e] = fmaf(A1[q][1], wv[1], acc1[e]);
                acc1[e] = fmaf(A1[q][2], wv[2], acc1[e]);
                acc1[e] = fmaf(A1[q][3], wv[3], acc1[e]);
            }
            // staggered depth-2 refill: A*[q] dead after this q-phase
            if (t + 2 < TPW) {
                A0[q] = *(const f32x4*)(pnext + q * 256);
                A1[q] = *(const f32x4*)(pnext + H + q * 256);
            }
        }
        if (t + 2 < TPW) pnext += 2 * H;

        const float u0v = rscatter(acc0[0], acc0[1], acc0[2], acc0[3],
                                   acc0[4], acc0[5], acc0[6], acc0[7]);
        const float u1v = rscatter(acc1[0], acc1[1], acc1[2], acc1[3],
                                   acc1[4], acc1[5], acc1[6], acc1[7]);
        mylog = (g == t)     ? u0v : mylog;
        mylog = (g == t + 1) ? u1v : mylog;
    }

    // --- epilogue: softmax + top-2 within each 8-lane group (masks 1,2,4) ---
    float mx = mylog;
    mx = fmaxf(mx, __shfl_xor(mx, 1));
    mx = fmaxf(mx, __shfl_xor(mx, 2));
    mx = fmaxf(mx, __shfl_xor(mx, 4));
    float pe = expf(mylog - mx);
    float s = pe;
    s += __shfl_xor(s, 1); s += __shfl_xor(s, 2); s += __shfl_xor(s, 4);
    pe = pe / s;

    // top-1 (max, lowest index on ties — lax.top_k semantics)
    float v1 = pe; int i1 = eo;
#pragma unroll
    for (int m = 1; m <= 4; m <<= 1) {
        const float ov = __shfl_xor(v1, m);
        const int   oi = __shfl_xor(i1, m);
        const bool take = (ov > v1) || (ov == v1 && oi < i1);
        v1 = take ? ov : v1; i1 = take ? oi : i1;
    }
    // top-2: exclude winner (probs > 0 always, so -1 is a safe sentinel)
    float v2 = (eo == i1) ? -1.f : pe; int i2 = eo;
#pragma unroll
    for (int m = 1; m <= 4; m <<= 1) {
        const float ov = __shfl_xor(v2, m);
        const int   oi = __shfl_xor(i2, m);
        const bool take = (ov > v2) || (ov == v2 && oi < i2);
        v2 = take ? ov : v2; i2 = take ? oi : i2;
    }
    const float s12 = v1 + v2;
    const float d = (eo == i1) ? (v1 / s12) : ((eo == i2) ? (v2 / s12) : 0.f);

    // stores: one dword/lane, 256B contiguous per wave
    dispatch[tok0 * E + lane]  = d;
    probs_out[tok0 * E + lane] = pe;

    // per-wave slot sums: slot e = dispatch mass, slot 8+e = prob sum
    float ds = d, ps = pe;
    ds += __shfl_xor(ds, 8);  ps += __shfl_xor(ps, 8);
    ds += __shfl_xor(ds, 16); ps += __shfl_xor(ps, 16);
    ds += __shfl_xor(ds, 32); ps += __shfl_xor(ps, 32);
    if (lane < 8) { red[wave][eo] = ds; red[wave][8 + eo] = ps; }
    __syncthreads();
    if (tid < 16) {
        const float acc = red[0][tid] + red[1][tid] + red[2][tid] + red[3][tid];
        partial[(size_t)tid * gridDim.x + blockIdx.x] = acc;   // slot-major
    }
}

// ---------------------------------------------------------------------------
// Kernel 2: reduce partials -> lb_loss; per-expert capacity enforcement
// (exact radix select, index-ordered ties). Early-exits when under capacity
// (always, in expectation: E[mass/expert]=4096 < 5120 -- insurance path).
// ---------------------------------------------------------------------------
__global__ __launch_bounds__(FBLK) void finalize_kernel(
    float* __restrict__ dispatch,
    const float* __restrict__ partial,
    int nb,
    float* __restrict__ lb_out,
    int N)
{
    const int e    = blockIdx.x;
    const int tid  = threadIdx.x;
    const int lane = tid & 63;
    const int wv   = tid >> 6;           // 16 waves -> 16 slots

    __shared__ float g[16];
    {
        float v = 0.f;
        for (int b = lane; b < nb; b += 64) v += partial[(size_t)wv * nb + b];
#pragma unroll
        for (int off = 32; off; off >>= 1) v += __shfl_xor(v, off);
        if (lane == 0) g[wv] = v;
    }
    __syncthreads();

    if (e == 0 && tid == 0) {
        float s = 0.f;
        for (int i = 0; i < E; ++i) s += g[i] * g[E + i];
        *lb_out = 0.01f * s / (float)N;
    }

    const float tpe = g[e];
    if (!(tpe > (float)CAP)) return;     // block-uniform

    __shared__ unsigned hist[256];
    __shared__ unsigned sh_prefix;
    __shared__ int sh_k;

    unsigned prefix = 0;
    int k = CAP;

    for (int round = 0; round < 4; ++round) {
        const int shift = 24 - 8 * round;
        for (int i = tid; i < 256; i += FBLK) hist[i] = 0;
        __syncthreads();
        const unsigned mhi = (round == 0) ? 0u : (0xFFFFFFFFu << (shift + 8));
        for (int i = tid; i < N; i += FBLK) {
            const unsigned bits = __float_as_uint(dispatch[(size_t)i * E + e]);
            if ((bits & mhi) == (prefix & mhi))
                atomicAdd(&hist[(bits >> shift) & 255u], 1u);
        }
        __syncthreads();
        if (tid == 0) {
            int cum = 0;
            int d = 255;
            for (; d > 0; --d) {
                const int h = (int)hist[d];
                if (cum + h >= k) break;
                cum += h;
            }
            sh_prefix = prefix | ((unsigned)d << shift);
            sh_k = k - cum;
        }
        __syncthreads();
        prefix = sh_prefix;
        k = sh_k;
        __syncthreads();
    }

    const unsigned T = prefix;
    const unsigned r = (unsigned)k;

    __shared__ unsigned wave_cnt[FBLK / 64];
    __shared__ unsigned running;
    if (tid == 0) running = 0;
    __syncthreads();

    for (int base = 0; base < N; base += FBLK) {
        const int i = base + tid;
        const unsigned bits = __float_as_uint(dispatch[(size_t)i * E + e]);
        const bool eq = (bits == T);
        const unsigned long long bal = __ballot(eq);
        if (lane == 0) wave_cnt[wv] = (unsigned)__popcll(bal);
        __syncthreads();
        unsigned before = running;
        for (int w = 0; w < wv; ++w) before += wave_cnt[w];
        const unsigned rank = before + (unsigned)__popcll(bal & ((1ull << lane) - 1ull));
        const bool keep = (bits > T) || (eq && rank < r);
        if (!keep) dispatch[(size_t)i * E + e] = 0.f;
        __syncthreads();
        if (tid == 0) {
            unsigned tot = 0;
            for (int w = 0; w < FBLK / 64; ++w) tot += wave_cnt[w];
            running += tot;
        }
        __syncthreads();
    }
}

// ---------------------------------------------------------------------------
extern "C" void kernel_launch(void* const* d_in, const int* in_sizes, int n_in,
                              void* d_out, int out_size, void* d_ws, size_t ws_size,
                              hipStream_t stream)
{
    const float* hs = (const float*)d_in[0];
    const float* rw = (const float*)d_in[1];
    const int n_tokens = in_sizes[0] / H;          // 32768

    float* dispatch = (float*)d_out;               // [N*E]
    float* lb       = dispatch + (size_t)n_tokens * E;
    float* probs    = lb + 1;                      // [N*E]
    float* partial  = (float*)d_ws;                // [16][nb] fp32, fully written

    const int nb = n_tokens / (4 * TPW);           // 1024 blocks, 32 tokens each
    router_kernel<<<nb, BLK, 0, stream>>>(hs, rw, dispatch, probs, partial);
    finalize_kernel<<<E, FBLK, 0, stream>>>(dispatch, partial, nb, lb, n_tokens);
}

// Round 6
// 197.367 us; speedup vs baseline: 1.4921x; 1.4921x over previous
//
#include <hip/hip_runtime.h>

#define H 1024
#define E 8
#define BLK 256
#define CAP 5120       // int(1.25 * 4096 * 8 / 8)
#define FBLK 1024
#define TPW 8          // tokens per wave

typedef float f32x4 __attribute__((ext_vector_type(4)));

// ---------------------------------------------------------------------------
// Kernel 1: contiguous-stream GEMV.
// SESSION RULE (R0-R5 counters): this toolchain's VGPR cap = 256/arg2 of
// __launch_bounds__ (arg 5->48, 4->64, 2->128 measured). LDS=33KB already
// caps occupancy at 4 blocks/CU, so arg>2 buys NO occupancy and only
// strangles the allocator: R3/R4's (256,4) forced a ~100-reg design into 64
// VGPRs -> 434B/thread spill round-trips = 114MB excess WRITE, 40MB excess
// FETCH, VALUBusy 8%. R5's rolled t-loop re-stored spills per iteration ->
// even worse (644B/thread). Fix: __launch_bounds__(BLK,2) -> cap 128 >=
// demand (~100) -> zero spill; occupancy still LDS-capped 16 waves/CU.
// Full t-loop unroll (R3/R4 variant, faster than rolled R5).
// Design (validated: 0 bank conflicts, occ 40%):
//  - w in LDS (32KB); lane l reads w[e][q] at (e*1024+q*256+4l): 16B/lane
//    contiguous ds_read_b128, conflict-free; reused across 2 tokens.
//  - hs loads 1KB-contiguous per wave (lane l owns floats {4l+256q} of one
//    row), depth-2 token prefetch staggered through the q-loop.
//  - reduce-scatter (masks 1,2,4 keep/send, 8,16,32 add) -> lane 8g+e holds
//    logit(token g, expert e); 10 shfl/token.
//  - epilogue: group-of-8 softmax/top2 butterflies, all 64 lanes active;
//    dispatch/probs stores one dword/lane, 256B contiguous.
// ---------------------------------------------------------------------------
__global__ __launch_bounds__(BLK, 2) void router_kernel(
    const float* __restrict__ hs,
    const float* __restrict__ rw,
    float* __restrict__ dispatch,
    float* __restrict__ probs_out,
    float* __restrict__ partial)   // [16][nb] slot-major
{
    __shared__ float w_lds[E * H];   // 32 KB
    __shared__ float red[4][16];

    const int tid  = threadIdx.x;
    const int wave = tid >> 6;
    const int lane = tid & 63;
    const int g    = lane >> 3;      // token group within wave (0..7)
    const int eo   = lane & 7;       // owned expert
    const size_t tok0 = ((size_t)blockIdx.x * (BLK / 64) + wave) * TPW;
    const float* h0 = hs + tok0 * H + 4 * lane;

    // depth-2 token prefetch (8 x 1KB contiguous wave-loads), issued before
    // the w staging so the HBM round-trip overlaps it
    f32x4 A0[4], A1[4];
#pragma unroll
    for (int q = 0; q < 4; ++q) A0[q] = *(const f32x4*)(h0 + q * 256);
#pragma unroll
    for (int q = 0; q < 4; ++q) A1[q] = *(const f32x4*)(h0 + H + q * 256);

    for (int i = tid; i < E * H / 4; i += BLK)
        ((f32x4*)w_lds)[i] = ((const f32x4*)rw)[i];
    __syncthreads();

    const int b0 = lane & 1, b1 = (lane >> 1) & 1, b2 = (lane >> 2) & 1;

    // reduce-scatter over the 8-expert set (inputs by value; all-SSA after
    // inlining). Output: full dot for expert (lane&7), replicated over the
    // 8-lane groups.
    auto rscatter = [&](float a0, float a1, float a2, float a3,
                        float a4, float a5, float a6, float a7) -> float {
        float r0 = b0 ? a1 : a0, s0 = b0 ? a0 : a1;
        float r1 = b0 ? a3 : a2, s1 = b0 ? a2 : a3;
        float r2 = b0 ? a5 : a4, s2 = b0 ? a4 : a5;
        float r3 = b0 ? a7 : a6, s3 = b0 ? a6 : a7;
        r0 += __shfl_xor(s0, 1); r1 += __shfl_xor(s1, 1);
        r2 += __shfl_xor(s2, 1); r3 += __shfl_xor(s3, 1);
        float t0 = b1 ? r1 : r0, u0 = b1 ? r0 : r1;
        float t1 = b1 ? r3 : r2, u1 = b1 ? r2 : r3;
        t0 += __shfl_xor(u0, 2); t1 += __shfl_xor(u1, 2);
        float v = b2 ? t1 : t0, x = b2 ? t0 : t1;
        v += __shfl_xor(x, 4);
        v += __shfl_xor(v, 8);
        v += __shfl_xor(v, 16);
        v += __shfl_xor(v, 32);
        return v;                 // logit for expert 4*b2+2*b1+b0 = lane&7
    };

    float mylog = 0.f;            // latched logit for (token tok0+g, expert eo)
    const float* pnext = h0 + 2 * H;

#pragma unroll
    for (int t = 0; t < TPW; t += 2) {
        float acc0[E], acc1[E];
#pragma unroll
        for (int e = 0; e < E; ++e) { acc0[e] = 0.f; acc1[e] = 0.f; }

#pragma unroll
        for (int q = 0; q < 4; ++q) {
            const float* wb = w_lds + q * 256 + 4 * lane;
#pragma unroll
            for (int e = 0; e < E; ++e) {
                const f32x4 wv = *(const f32x4*)(wb + e * H);
                acc0[e] = fmaf(A0[q][0], wv[0], acc0[e]);
                acc0[e] = fmaf(A0[q][1], wv[1], acc0[e]);
                acc0[e] = fmaf(A0[q][2], wv[2], acc0[e]);
                acc0[e] = fmaf(A0[q][3], wv[3], acc0[e]);
                acc1[e] = fmaf(A1[q][0], wv[0], acc1[e]);
                acc1[e] = fmaf(A1[q][1], wv[1], acc1[e]);
                acc1[e] = fmaf(A1[q][2], wv[2], acc1[e]);
                acc1[e] = fmaf(A1[q][3], wv[3], acc1[e]);
            }
            // staggered depth-2 refill: A*[q] dead after this q-phase
            if (t + 2 < TPW) {
                A0[q] = *(const f32x4*)(pnext + q * 256);
                A1[q] = *(const f32x4*)(pnext + H + q * 256);
            }
        }
        if (t + 2 < TPW) pnext += 2 * H;

        const float u0v = rscatter(acc0[0], acc0[1], acc0[2], acc0[3],
                                   acc0[4], acc0[5], acc0[6], acc0[7]);
        const float u1v = rscatter(acc1[0], acc1[1], acc1[2], acc1[3],
                                   acc1[4], acc1[5], acc1[6], acc1[7]);
        mylog = (g == t)     ? u0v : mylog;
        mylog = (g == t + 1) ? u1v : mylog;
    }

    // --- epilogue: softmax + top-2 within each 8-lane group (masks 1,2,4) ---
    float mx = mylog;
    mx = fmaxf(mx, __shfl_xor(mx, 1));
    mx = fmaxf(mx, __shfl_xor(mx, 2));
    mx = fmaxf(mx, __shfl_xor(mx, 4));
    float pe = expf(mylog - mx);
    float s = pe;
    s += __shfl_xor(s, 1); s += __shfl_xor(s, 2); s += __shfl_xor(s, 4);
    pe = pe / s;

    // top-1 (max, lowest index on ties — lax.top_k semantics)
    float v1 = pe; int i1 = eo;
#pragma unroll
    for (int m = 1; m <= 4; m <<= 1) {
        const float ov = __shfl_xor(v1, m);
        const int   oi = __shfl_xor(i1, m);
        const bool take = (ov > v1) || (ov == v1 && oi < i1);
        v1 = take ? ov : v1; i1 = take ? oi : i1;
    }
    // top-2: exclude winner (probs > 0 always, so -1 is a safe sentinel)
    float v2 = (eo == i1) ? -1.f : pe; int i2 = eo;
#pragma unroll
    for (int m = 1; m <= 4; m <<= 1) {
        const float ov = __shfl_xor(v2, m);
        const int   oi = __shfl_xor(i2, m);
        const bool take = (ov > v2) || (ov == v2 && oi < i2);
        v2 = take ? ov : v2; i2 = take ? oi : i2;
    }
    const float s12 = v1 + v2;
    const float d = (eo == i1) ? (v1 / s12) : ((eo == i2) ? (v2 / s12) : 0.f);

    // stores: one dword/lane, 256B contiguous per wave
    dispatch[tok0 * E + lane]  = d;
    probs_out[tok0 * E + lane] = pe;

    // per-wave slot sums: slot e = dispatch mass, slot 8+e = prob sum
    float ds = d, ps = pe;
    ds += __shfl_xor(ds, 8);  ps += __shfl_xor(ps, 8);
    ds += __shfl_xor(ds, 16); ps += __shfl_xor(ps, 16);
    ds += __shfl_xor(ds, 32); ps += __shfl_xor(ps, 32);
    if (lane < 8) { red[wave][eo] = ds; red[wave][8 + eo] = ps; }
    __syncthreads();
    if (tid < 16) {
        const float acc = red[0][tid] + red[1][tid] + red[2][tid] + red[3][tid];
        partial[(size_t)tid * gridDim.x + blockIdx.x] = acc;   // slot-major
    }
}

// ---------------------------------------------------------------------------
// Kernel 2: reduce partials -> lb_loss; per-expert capacity enforcement
// (exact radix select, index-ordered ties). Early-exits when under capacity
// (always, in expectation: E[mass/expert]=4096 < 5120 -- insurance path).
// ---------------------------------------------------------------------------
__global__ __launch_bounds__(FBLK) void finalize_kernel(
    float* __restrict__ dispatch,
    const float* __restrict__ partial,
    int nb,
    float* __restrict__ lb_out,
    int N)
{
    const int e    = blockIdx.x;
    const int tid  = threadIdx.x;
    const int lane = tid & 63;
    const int wv   = tid >> 6;           // 16 waves -> 16 slots

    __shared__ float g[16];
    {
        float v = 0.f;
        for (int b = lane; b < nb; b += 64) v += partial[(size_t)wv * nb + b];
#pragma unroll
        for (int off = 32; off; off >>= 1) v += __shfl_xor(v, off);
        if (lane == 0) g[wv] = v;
    }
    __syncthreads();

    if (e == 0 && tid == 0) {
        float s = 0.f;
        for (int i = 0; i < E; ++i) s += g[i] * g[E + i];
        *lb_out = 0.01f * s / (float)N;
    }

    const float tpe = g[e];
    if (!(tpe > (float)CAP)) return;     // block-uniform

    __shared__ unsigned hist[256];
    __shared__ unsigned sh_prefix;
    __shared__ int sh_k;

    unsigned prefix = 0;
    int k = CAP;

    for (int round = 0; round < 4; ++round) {
        const int shift = 24 - 8 * round;
        for (int i = tid; i < 256; i += FBLK) hist[i] = 0;
        __syncthreads();
        const unsigned mhi = (round == 0) ? 0u : (0xFFFFFFFFu << (shift + 8));
        for (int i = tid; i < N; i += FBLK) {
            const unsigned bits = __float_as_uint(dispatch[(size_t)i * E + e]);
            if ((bits & mhi) == (prefix & mhi))
                atomicAdd(&hist[(bits >> shift) & 255u], 1u);
        }
        __syncthreads();
        if (tid == 0) {
            int cum = 0;
            int d = 255;
            for (; d > 0; --d) {
                const int h = (int)hist[d];
                if (cum + h >= k) break;
                cum += h;
            }
            sh_prefix = prefix | ((unsigned)d << shift);
            sh_k = k - cum;
        }
        __syncthreads();
        prefix = sh_prefix;
        k = sh_k;
        __syncthreads();
    }

    const unsigned T = prefix;
    const unsigned r = (unsigned)k;

    __shared__ unsigned wave_cnt[FBLK / 64];
    __shared__ unsigned running;
    if (tid == 0) running = 0;
    __syncthreads();

    for (int base = 0; base < N; base += FBLK) {
        const int i = base + tid;
        const unsigned bits = __float_as_uint(dispatch[(size_t)i * E + e]);
        const bool eq = (bits == T);
        const unsigned long long bal = __ballot(eq);
        if (lane == 0) wave_cnt[wv] = (unsigned)__popcll(bal);
        __syncthreads();
        unsigned before = running;
        for (int w = 0; w < wv; ++w) before += wave_cnt[w];
        const unsigned rank = before + (unsigned)__popcll(bal & ((1ull << lane) - 1ull));
        const bool keep = (bits > T) || (eq && rank < r);
        if (!keep) dispatch[(size_t)i * E + e] = 0.f;
        __syncthreads();
        if (tid == 0) {
            unsigned tot = 0;
            for (int w = 0; w < FBLK / 64; ++w) tot += wave_cnt[w];
            running += tot;
        }
        __syncthreads();
    }
}

// ---------------------------------------------------------------------------
extern "C" void kernel_launch(void* const* d_in, const int* in_sizes, int n_in,
                              void* d_out, int out_size, void* d_ws, size_t ws_size,
                              hipStream_t stream)
{
    const float* hs = (const float*)d_in[0];
    const float* rw = (const float*)d_in[1];
    const int n_tokens = in_sizes[0] / H;          // 32768

    float* dispatch = (float*)d_out;               // [N*E]
    float* lb       = dispatch + (size_t)n_tokens * E;
    float* probs    = lb + 1;                      // [N*E]
    float* partial  = (float*)d_ws;                // [16][nb] fp32, fully written

    const int nb = n_tokens / (4 * TPW);           // 1024 blocks, 32 tokens each
    router_kernel<<<nb, BLK, 0, stream>>>(hs, rw, dispatch, probs, partial);
    finalize_kernel<<<E, FBLK, 0, stream>>>(dispatch, partial, nb, lb, n_tokens);
}